// Round 12
// baseline (182.927 us; speedup 1.0000x reference)
//
#include <hip/hip_runtime.h>
#include <hip/hip_bf16.h>
#include <stdint.h>

#define M_DIM 4096
#define N_DIM 4096
#define K_DIM 4096
#define NH 128
#define NW 128
#define NKT2 128   // K-tiles of BK=32

typedef short bf16x8 __attribute__((ext_vector_type(8)));
typedef short bf16x4 __attribute__((ext_vector_type(4)));
typedef float f32x4 __attribute__((ext_vector_type(4)));

#define MFMA(a, b, c) __builtin_amdgcn_mfma_f32_16x16x32_bf16((a), (b), (c), 0, 0, 0)

__device__ __forceinline__ short f2bf(float f) {
  union { float f; unsigned u; } c; c.f = f;
  unsigned u = c.u;
  unsigned r = (u + 0x7fffu + ((u >> 16) & 1u)) >> 16;  // RNE
  return (short)r;
}

// ------- kernel 1: fused per-block mask + masked weight f32->bf16 ----------
__global__ __launch_bounds__(256) void k_mask_weight(const int* __restrict__ mask,
                                                     const float* __restrict__ conv_bias,
                                                     const float* __restrict__ w,
                                                     int* __restrict__ bm,
                                                     short* __restrict__ ob) {
  const int bw = blockIdx.x, bh = blockIdx.y;   // bw = k-block, bh = n-block
  const int t = threadIdx.x;
  const int row = t >> 3;
  const int c4 = (t & 7) << 2;
  const size_t off = (size_t)(bh * 32 + row) * K_DIM + bw * 32 + c4;

  int4 v = *(const int4*)(mask + off);
  int s = v.x + v.y + v.z + v.w;
#pragma unroll
  for (int o = 32; o > 0; o >>= 1) s += __shfl_down(s, o);
  __shared__ int red[4];
  __shared__ int active;
  if ((t & 63) == 0) red[t >> 6] = s;
  __syncthreads();
  if (t == 0) {
    float tot = (float)(red[0] + red[1] + red[2] + red[3]) + conv_bias[0];
    int a = (tot > 0.0f) ? 1 : 0;
    bm[bh * NW + bw] = a;
    active = a;
  }
  __syncthreads();

  bf16x4 o;
  if (active) {
    f32x4 wv = *(const f32x4*)(w + off);
    o[0] = f2bf(wv[0]); o[1] = f2bf(wv[1]); o[2] = f2bf(wv[2]); o[3] = f2bf(wv[3]);
  } else {
    o[0] = 0; o[1] = 0; o[2] = 0; o[3] = 0;
  }
  *(bf16x4*)(ob + off) = o;
}

// ---------------- kernel 2: data f32 -> bf16 ----------------
__global__ __launch_bounds__(256) void k_cvt_data(const float* __restrict__ in,
                                                  short* __restrict__ ob) {
  size_t i = (size_t)blockIdx.x * 256 + threadIdx.x;
  f32x4 v = ((const f32x4*)in)[i];
  bf16x4 o;
  o[0] = f2bf(v[0]); o[1] = f2bf(v[1]); o[2] = f2bf(v[2]); o[3] = f2bf(v[3]);
  ((bf16x4*)ob)[i] = o;
}

// -------- kernel 3: 128x256 GEMM, BK=32, triple-buffer, 2 WGs/CU -----------
// 512 WGs (2/CU -> TLP hides barrier/vmcnt stalls); 8 waves 2x4 (64x64/wave,
// acc[4][4]); LDS 72KB/WG (3 bufs x (A 8KB + B 16KB)). Staging runs 2 tiles
// ahead (3 glls/tile) with counted VMW(3) (never 0 mid-loop); ONE barrier +
// ONE vmcnt per tile. BK=32 = one mask k-block/tile: per-wave gates e0/e1
// (2 n-blocks of its 64 cols) skip reads+MFMAs; zeroed weights keep exactness.
__global__ __launch_bounds__(512, 2) void k_gemm256(const short* __restrict__ Ab,
                                                    const short* __restrict__ Bb,
                                                    const float* __restrict__ bias,
                                                    const int* __restrict__ bm,
                                                    float* __restrict__ out) {
  __shared__ short Asm[3][128][32];  // 24 KB
  __shared__ short Bsm[3][256][32];  // 48 KB

  const int tid = threadIdx.x;
  const int wid = tid >> 6, lane = tid & 63;
  const int wr = wid >> 2, wc = wid & 3;
  const int r = lane & 15, g0 = lane >> 4;
  const int gs = g0 ^ ((r >> 1) & 3);      // swizzled col-seg for ds_read

  // XCD-aware swizzle: 512 wgs, 8 XCDs, 64/XCD (bijective since 512%8==0)
  const int swz = (blockIdx.x & 7) * 64 + (blockIdx.x >> 3);
  const int bx = swz & 15, by = swz >> 4;   // 16 col-tiles x 32 row-tiles
  const int rowM = by * 128, colN = bx * 256;

  // staging geometry: 512 thr x 16B = 8KB region, linear LDS dest
  const int srow = tid >> 2;
  const int sseg = (tid & 3) ^ ((tid >> 3) & 3);   // pre-swizzled source seg
  const int swave = wid * 512;                     // wave-uniform base (shorts)

  const short* gA = Ab + (size_t)(rowM + srow) * K_DIM + sseg * 8;
  const short* gB = Bb + (size_t)(colN + srow) * K_DIM + sseg * 8;
  const size_t HOFF = (size_t)128 * K_DIM;

  // per-wave mask bits: its 2 n-block rows of bm, 128 k-blocks -> 4x u64
  const int nb0 = (colN >> 5) + wc * 2;
  const int* bp = bm + (size_t)nb0 * NW;
  unsigned long long w0l = __ballot(bp[lane] != 0);
  unsigned long long w0h = __ballot(bp[64 + lane] != 0);
  unsigned long long w1l = __ballot(bp[NW + lane] != 0);
  unsigned long long w1h = __ballot(bp[NW + 64 + lane] != 0);
  __builtin_amdgcn_sched_barrier(0);  // mask loads retired before staging

#define GLL(g, l)                                                            \
  __builtin_amdgcn_global_load_lds((const __attribute__((address_space(1))) void*)(g), \
                                   (__attribute__((address_space(3))) void*)(l), 16, 0, 0)
#define STA(SBUF, kt) GLL(gA + (size_t)(kt) * 32, &Asm[SBUF][0][0] + swave)
#define STBH(SBUF, kt, h) GLL(gB + HOFF * (h) + (size_t)(kt) * 32, \
                              &Bsm[SBUF][(h) * 128][0] + swave)

#define LDA(BUF, m) (*(const bf16x8*)&Asm[BUF][wr * 64 + (m) * 16 + r][gs * 8])
#define LDB(BUF, n) (*(const bf16x8*)&Bsm[BUF][wc * 64 + (n) * 16 + r][gs * 8])

#define MF4(bb, n)                                                           \
  acc[0][n] = MFMA(aX0, bb, acc[0][n]); acc[1][n] = MFMA(aX1, bb, acc[1][n]); \
  acc[2][n] = MFMA(aX2, bb, acc[2][n]); acc[3][n] = MFMA(aX3, bb, acc[3][n]);

#define BAR __builtin_amdgcn_s_barrier()
#define SB0 __builtin_amdgcn_sched_barrier(0)
#define PRIO1 __builtin_amdgcn_s_setprio(1)
#define PRIO0 __builtin_amdgcn_s_setprio(0)
#define VMW_(N) asm volatile("s_waitcnt vmcnt(" #N ")" ::: "memory")
#define VMW(N) VMW_(N)

// One BK=32 tile: gated reads -> stage trio(u+2) into SBUF -> gated MFMAs
// -> VMW -> barrier. buf[u%3] is next written during tile u+1 (after the
// tile-u-end barrier retires all reads). VMW(3) = trio(u+1) landed.
#define TILE(BUF, SBUF, u, SG, VM)                                           \
  {                                                                          \
    const int kb = (u);                                                      \
    const int e0 = (int)((((kb) & 64) ? w0h : w0l) >> ((kb) & 63)) & 1;      \
    const int e1 = (int)((((kb) & 64) ? w1h : w1l) >> ((kb) & 63)) & 1;      \
    bf16x8 aX0, aX1, aX2, aX3, b0, b1, b2, b3;                               \
    if (e0 | e1) { aX0 = LDA(BUF, 0); aX1 = LDA(BUF, 1);                     \
                   aX2 = LDA(BUF, 2); aX3 = LDA(BUF, 3); }                   \
    if (e0) { b0 = LDB(BUF, 0); b1 = LDB(BUF, 1); }                          \
    if (e1) { b2 = LDB(BUF, 2); b3 = LDB(BUF, 3); }                          \
    if (SG) { STA(SBUF, (u) + 2); STBH(SBUF, (u) + 2, 0); STBH(SBUF, (u) + 2, 1); } \
    PRIO1;                                                                   \
    if (e0) { MF4(b0, 0) MF4(b1, 1) }                                        \
    if (e1) { MF4(b2, 2) MF4(b3, 3) }                                        \
    PRIO0;                                                                   \
    VMW(VM); BAR; SB0;                                                       \
  }

  f32x4 acc[4][4];
#pragma unroll
  for (int m = 0; m < 4; ++m)
#pragma unroll
    for (int n = 0; n < 4; ++n) acc[m][n] = (f32x4){0.f, 0.f, 0.f, 0.f};

  // prologue: stage trio(0), trio(1); wait trio(0); barrier.
  STA(0, 0); STBH(0, 0, 0); STBH(0, 0, 1);
  STA(1, 1); STBH(1, 1, 0); STBH(1, 1, 1);
  VMW(3);
  BAR; SB0;

#pragma unroll 1
  for (int u = 0; u < 126; u += 3) {
    TILE(0, 2, u, 1, 3);
    TILE(1, 0, u + 1, 1, 3);
    TILE(2, 1, u + 2, 1, 3);
  }
  TILE(0, 0, 126, 0, 0);   // trio(127) 2 tiles old -> drain is cheap
  TILE(1, 0, 127, 0, 0);

  // epilogue: C/D col=lane&15 (=r), row=(lane>>4)*4+j (=g0*4+j)
  const int orow = rowM + wr * 64;
  const int ocol = colN + wc * 64;
#pragma unroll
  for (int n = 0; n < 4; ++n) {
    int col = ocol + n * 16 + r;
    float bz = bias[col];
#pragma unroll
    for (int m = 0; m < 4; ++m) {
      int row0 = orow + m * 16 + g0 * 4;
#pragma unroll
      for (int j = 0; j < 4; ++j)
        out[(size_t)(row0 + j) * N_DIM + col] = acc[m][n][j] + bz;
    }
  }
#undef TILE
#undef GLL
#undef STA
#undef STBH
#undef LDA
#undef LDB
#undef MF4
#undef BAR
#undef SB0
#undef PRIO1
#undef PRIO0
#undef VMW
#undef VMW_
}

// ---------------- fallback (ws too small): naive fp32 ----------------
__global__ __launch_bounds__(256) void k_naive(const float* __restrict__ A,
                                               const float* __restrict__ W,
                                               const float* __restrict__ bias,
                                               const int* __restrict__ bm,
                                               float* __restrict__ out) {
  int col = blockIdx.x * 16 + (threadIdx.x & 15);
  int row = blockIdx.y * 16 + (threadIdx.x >> 4);
  float s = 0.f;
  for (int kb = 0; kb < K_DIM / 32; ++kb) {
    if (bm[(col >> 5) * NW + kb]) {
      int kbase = kb * 32;
#pragma unroll 8
      for (int k = 0; k < 32; ++k)
        s += A[(size_t)row * K_DIM + kbase + k] * W[(size_t)col * K_DIM + kbase + k];
    }
  }
  out[(size_t)row * N_DIM + col] = s + bias[col];
}

__global__ __launch_bounds__(256) void k_block_mask(const int* __restrict__ mask,
                                                    const float* __restrict__ conv_bias,
                                                    int* __restrict__ bm) {
  const int bw = blockIdx.x, bh = blockIdx.y;
  const int t = threadIdx.x;
  const int row = t >> 3;
  const int c4 = (t & 7) << 2;
  const int4* p = (const int4*)(mask + (size_t)(bh * 32 + row) * K_DIM + bw * 32 + c4);
  int4 v = *p;
  int s = v.x + v.y + v.z + v.w;
#pragma unroll
  for (int off = 32; off > 0; off >>= 1) s += __shfl_down(s, off);
  __shared__ int red[4];
  if ((t & 63) == 0) red[t >> 6] = s;
  __syncthreads();
  if (t == 0) {
    float tot = (float)(red[0] + red[1] + red[2] + red[3]) + conv_bias[0];
    bm[bh * NW + bw] = (tot > 0.0f) ? 1 : 0;
  }
}

extern "C" void kernel_launch(void* const* d_in, const int* in_sizes, int n_in,
                              void* d_out, int out_size, void* d_ws, size_t ws_size,
                              hipStream_t stream) {
  const float* data = (const float*)d_in[0];
  const float* weight = (const float*)d_in[1];
  const float* bias = (const float*)d_in[2];
  const int* mask = (const int*)d_in[3];
  const float* conv_bias = (const float*)d_in[4];
  float* out = (float*)d_out;

  int* bm = (int*)d_ws;
  const size_t off_a = 65536;
  const size_t off_b = off_a + (size_t)M_DIM * K_DIM * 2;
  const size_t needed = off_b + (size_t)N_DIM * K_DIM * 2;

  if (ws_size >= needed) {
    short* Abf = (short*)((char*)d_ws + off_a);
    short* Wbf = (short*)((char*)d_ws + off_b);
    k_mask_weight<<<dim3(NW, NH), 256, 0, stream>>>(mask, conv_bias, weight, bm, Wbf);
    k_cvt_data<<<dim3((M_DIM * (K_DIM / 4)) / 256), 256, 0, stream>>>(data, Abf);
    k_gemm256<<<dim3(512), 512, 0, stream>>>(Abf, Wbf, bias, bm, out);
  } else {
    k_block_mask<<<dim3(NW, NH), 256, 0, stream>>>(mask, conv_bias, bm);
    k_naive<<<dim3(N_DIM / 16, M_DIM / 16), 256, 0, stream>>>(data, weight, bias, bm, out);
  }
}